// Round 3
// baseline (264.458 us; speedup 1.0000x reference)
//
#include <hip/hip_runtime.h>
#include <stdint.h>
#include <stddef.h>

// CapsuleFC: B=64, N_IN=2048, D_IN=16, N_OUT=64, D_OUT=16
constexpr int B_ = 64, N_ = 2048, A_ = 16, M_ = 64, D_ = 16;
constexpr float SCALE_ = 0.25f;   // 1/sqrt(16)
constexpr float EPS_ = 1e-6f;

typedef float f32x4 __attribute__((ext_vector_type(4)));

#define GLOAD_LDS16(g, l)                                                      \
  __builtin_amdgcn_global_load_lds((__attribute__((address_space(1))) void*)(g), \
                                   (__attribute__((address_space(3))) void*)(l), \
                                   16, 0, 0)

// compiler fence + hw barrier + fences (prevents IR/MIR motion across)
#define FULL_BAR() do {                         \
    asm volatile("" ::: "memory");              \
    __builtin_amdgcn_s_barrier();               \
    asm volatile("" ::: "memory");              \
    __builtin_amdgcn_sched_barrier(0);          \
  } while (0)

// grid: 2*nch blocks (flat, XCD-swizzled). block: 512 threads = 8 waves.
// wave wv owns batches b0..b0+3 (b0 = bg*32 + wv*4); lane l owns out-capsule m=l.
// Pipeline: n split into two 32KB a-halves, double-buffered LDS, counted vmcnt.
__global__ __launch_bounds__(512, 2) void caps_main(
    const float* __restrict__ input,   // [B,N,A]
    const float* __restrict__ cact,    // [B,N]
    const float* __restrict__ ncv,     // [B,M,D]
    const float* __restrict__ nact,    // [B,M]
    const float* __restrict__ w,       // [N,A,M,D]
    float* __restrict__ qk_out,        // [B,N,M]
    float* __restrict__ partial,       // [nch,B,M,D]
    int C, int nch)
{
  __shared__ __align__(128) char wl[2][32768];   // two a-half slabs (8 a-planes each)

  const int tid  = threadIdx.x;
  const int lane = tid & 63;
  const int wv   = __builtin_amdgcn_readfirstlane(tid >> 6);
  const int flat = blockIdx.x;
  int bg, ch;
  if (nch & 7) { bg = flat & 1; ch = flat >> 1; }
  else {       // XCD-bijective: both bgroups of chunk ch land on XCD ch%8
    bg = (flat >> 3) & 1;
    ch = ((flat >> 4) << 3) | (flat & 7);
  }
  const int b0 = bg * 32 + wv * 4;
  const int n0 = ch * C;

  // per-lane swizzled LDS read offsets: bits[6:4] ^= bits[9:7] (3-bit key)
  int offj[4];
#pragma unroll
  for (int j = 0; j < 4; ++j)
    offj[j] = (lane * 64 + j * 16) ^ (((lane >> 1) & 7) << 4);

  // hoisted per-(b,m) constants: next_act and next_capsule_value (m = lane)
  float na[4], cv[4][16];
#pragma unroll
  for (int bi = 0; bi < 4; ++bi) {
    na[bi] = nact[(b0 + bi) * M_ + lane];
    const float4* np4 = (const float4*)(ncv + ((size_t)(b0 + bi) * M_ + lane) * D_);
#pragma unroll
    for (int j = 0; j < 4; ++j) {
      const float4 t = np4[j];
      cv[bi][4 * j + 0] = t.x; cv[bi][4 * j + 1] = t.y;
      cv[bi][4 * j + 2] = t.z; cv[bi][4 * j + 3] = t.w;
    }
  }

  float acc[4][16];
#pragma unroll
  for (int i = 0; i < 4; ++i)
#pragma unroll
    for (int d = 0; d < 16; ++d) acc[i][d] = 0.f;

  float v[4][16];

  // ---- stage half-step h: 32KB of w[n0+h/2], a-half (h&1), into buf[h&1]
  auto STAGE = [&](int h) {
    const int n = n0 + (h >> 1);
    const char* ws = (const char*)w + ((size_t)n << 16) + ((size_t)(h & 1) << 15);
    char* lb = (char*)wl[h & 1] + wv * 1024;
#pragma unroll
    for (int i = 0; i < 4; ++i) {
      const uint32_t P = (uint32_t)(i * 8192 + tid * 16);      // physical byte
      const uint32_t S = P ^ (((P >> 7) & 7u) << 4);           // logical byte (involution)
      GLOAD_LDS16(ws + S, lb + i * 8192);
    }
  };

  // ---- compute half-step h from buf[h&1]
  auto COMPUTE = [&](int h) {
    const int n  = n0 + (h >> 1);
    const int ah = h & 1;
    const char* lb = (const char*)wl[ah];
    if (ah == 0) {
#pragma unroll
      for (int i = 0; i < 4; ++i)
#pragma unroll
        for (int d = 0; d < 16; ++d) v[i][d] = 0.f;
    }
    // input half-rows: scalar (uniform) loads -> lgkmcnt, not vmcnt
    float ib[4][8];
#pragma unroll
    for (int bi = 0; bi < 4; ++bi) {
      const int ibase = __builtin_amdgcn_readfirstlane(
          ((b0 + bi) * N_ + n) * A_ + ah * 8);
      const float4 r0 = *(const float4*)(input + ibase);
      const float4 r1 = *(const float4*)(input + ibase + 4);
      ib[bi][0] = r0.x; ib[bi][1] = r0.y; ib[bi][2] = r0.z; ib[bi][3] = r0.w;
      ib[bi][4] = r1.x; ib[bi][5] = r1.y; ib[bi][6] = r1.z; ib[bi][7] = r1.w;
    }
#pragma unroll
    for (int al = 0; al < 8; ++al) {
      float4 wr[4];
#pragma unroll
      for (int j = 0; j < 4; ++j)
        wr[j] = *(const float4*)(lb + al * 4096 + offj[j]);
#pragma unroll
      for (int bi = 0; bi < 4; ++bi) {
        const float x = ib[bi][al];
#pragma unroll
        for (int j = 0; j < 4; ++j) {
          v[bi][4 * j + 0] += x * wr[j].x;
          v[bi][4 * j + 1] += x * wr[j].y;
          v[bi][4 * j + 2] += x * wr[j].z;
          v[bi][4 * j + 3] += x * wr[j].w;
        }
      }
    }
    if (ah == 1) {
#pragma unroll
      for (int bi = 0; bi < 4; ++bi) {
        float s = 0.f;
#pragma unroll
        for (int d = 0; d < 16; ++d) s += v[bi][d] * cv[bi][d];
        s *= SCALE_;
        float mx = s;
#pragma unroll
        for (int off = 32; off >= 1; off >>= 1) mx = fmaxf(mx, __shfl_xor(mx, off, 64));
        const float e = __expf(s - mx);
        const float ena = e * na[bi];
        float Es = e, Ps = ena;
#pragma unroll
        for (int off = 32; off >= 1; off >>= 1) {
          Es += __shfl_xor(Es, off, 64);
          Ps += __shfl_xor(Ps, off, 64);
        }
        const float qk = ena / (Ps + 1e-10f * Es);
        __builtin_nontemporal_store(qk, qk_out + ((size_t)(b0 + bi) * N_ + n) * M_ + lane);
        float a_bn = cact[__builtin_amdgcn_readfirstlane((b0 + bi) * N_ + n)];
        a_bn = fminf(fmaxf(a_bn, EPS_), 1.0f - EPS_);
        const float wq = qk * a_bn;
#pragma unroll
        for (int d = 0; d < 16; ++d) acc[bi][d] += wq * v[bi][d];
      }
    }
  };

  const int HT = 2 * C;
  STAGE(0);
  for (int h = 0; h < HT - 1; ++h) {
    STAGE(h + 1);
    // wait for stage(h) only; stage(h+1) (4 loads) + qk stores (4, after odd computes)
    // remain in flight across the barrier (T4: counted vmcnt, never 0 in-loop)
    if (h == 0 || (h & 1)) asm volatile("s_waitcnt vmcnt(4)" ::: "memory");
    else                   asm volatile("s_waitcnt vmcnt(8)" ::: "memory");
    FULL_BAR();          // all waves' stage(h) landed
    COMPUTE(h);
    FULL_BAR();          // all waves done reading buf[h&1] before it's restaged
  }
  asm volatile("s_waitcnt vmcnt(0)" ::: "memory");
  FULL_BAR();
  COMPUTE(HT - 1);

  // partial[ch][b][m][d]
#pragma unroll
  for (int bi = 0; bi < 4; ++bi) {
    float* pp = partial + (((size_t)ch * B_ + (b0 + bi)) * M_ + lane) * D_;
#pragma unroll
    for (int j = 0; j < 4; ++j) {
      f32x4 t;
      t.x = acc[bi][4 * j + 0]; t.y = acc[bi][4 * j + 1];
      t.z = acc[bi][4 * j + 2]; t.w = acc[bi][4 * j + 3];
      __builtin_nontemporal_store(t, (f32x4*)pp + j);
    }
  }
}

__global__ void caps_reduce(const float* __restrict__ part,
                            const float* __restrict__ nain,
                            float* __restrict__ out, int nch)
{
  const int i = blockIdx.x * 256 + threadIdx.x;  // one thread per out[b,m,d]
  float s = 0.f;
  for (int c = 0; c < nch; ++c) s += part[(size_t)c * (B_ * M_ * D_) + i];
  out[i] = s;
  if (i < B_ * M_) out[B_ * M_ * D_ + i] = nain[i];  // next_act passthrough
}

extern "C" void kernel_launch(void* const* d_in, const int* in_sizes, int n_in,
                              void* d_out, int out_size, void* d_ws, size_t ws_size,
                              hipStream_t stream)
{
  const float* input = (const float*)d_in[0];
  const float* cact  = (const float*)d_in[1];
  const float* ncv   = (const float*)d_in[2];
  const float* nact  = (const float*)d_in[3];
  const float* w     = (const float*)d_in[4];

  float* out     = (float*)d_out;
  float* qk_out  = out + (B_ * M_ * D_) + (B_ * M_);   // after out and next_act
  float* partial = (float*)d_ws;

  int nch = 128;  // power of two so C divides N_ exactly; fits 33.6MB of ws
  while ((size_t)nch * (size_t)(B_ * M_ * D_) * sizeof(float) > ws_size && nch > 1) nch >>= 1;
  const int C = N_ / nch;

  hipLaunchKernelGGL(caps_main, dim3(2 * nch), dim3(512), 0, stream,
                     input, cact, ncv, nact, w, qk_out, partial, C, nch);
  hipLaunchKernelGGL(caps_reduce, dim3(B_ * M_ * D_ / 256), dim3(256), 0, stream,
                     partial, nact, out, nch);
}